// Round 2
// baseline (330.105 us; speedup 1.0000x reference)
//
#include <hip/hip_runtime.h>

constexpr int NBINS = 256;
constexpr int NWAVES = 16;   // 1024 threads / 64

// One block per (image, channel). Fully self-contained: histogram -> LUT ->
// apply, all in LDS. No global scratch, no cross-block communication.
__global__ __launch_bounds__(1024)
void equalize_fused(const int* __restrict__ in, int* __restrict__ out, int npix) {
    const int img = blockIdx.x / 3;
    const int ch  = blockIdx.x % 3;
    const int tid = threadIdx.x;
    const int nthreads = 1024;
    const int wave = tid >> 6;  // 0..15

    __shared__ int subh[NWAVES][NBINS];  // 16 KB sub-histograms
    __shared__ int cum[NBINS];
    __shared__ int lutI[NBINS];
    __shared__ int lastNZ;

    for (int i = tid; i < NWAVES * NBINS; i += nthreads) ((int*)subh)[i] = 0;
    if (tid == 0) lastNZ = 0;
    __syncthreads();

    const size_t base = (size_t)img * (size_t)(3 * npix);
    const int* inb = in + base;

    // ---- Phase 1: histogram of this channel ----
    for (int k = tid; k < npix; k += nthreads) {
        int v = inb[3 * k + ch] & 255;
        atomicAdd(&subh[wave][v], 1);
    }
    __syncthreads();

    // ---- Reduce sub-histograms ----
    int h = 0;
    if (tid < NBINS) {
        for (int w = 0; w < NWAVES; ++w) h += subh[w][tid];
        cum[tid] = h;
    }
    __syncthreads();
    if (tid < NBINS && h > 0) atomicMax(&lastNZ, tid);

    // ---- Inclusive scan (Hillis-Steele) over 256 bins ----
    // All 1024 threads execute the barriers; only tid<256 touch data.
    for (int off = 1; off < NBINS; off <<= 1) {
        int add = 0;
        if (tid < NBINS && tid >= off) add = cum[tid - off];
        __syncthreads();
        if (tid < NBINS) cum[tid] += add;
        __syncthreads();
    }

    // ---- Build LUT (reference semantics) ----
    if (tid < NBINS) {
        const int sum  = cum[NBINS - 1];
        const int last = lastNZ;
        const int hl   = cum[last] - (last > 0 ? cum[last - 1] : 0);  // histo[last]
        const int step = (sum - hl) / 255;
        int v;
        if (step == 0) {
            v = tid;  // reference: where(step==0, img, ...)
        } else {
            // final_lut[t] = clip((cumsum[t-1] + step//2)//step, 0, 255); final_lut[0]=0
            const int cp = (tid == 0) ? 0 : cum[tid - 1];
            v = (cp + (step >> 1)) / step;
            if (v > 255) v = 255;
        }
        lutI[tid] = v;
    }
    __syncthreads();

    // ---- Phase 2: apply LUT, write int32 output ----
    int* outb = out + base;
    for (int k = tid; k < npix; k += nthreads) {
        int v = inb[3 * k + ch] & 255;
        outb[3 * k + ch] = lutI[v];
    }
}

extern "C" void kernel_launch(void* const* d_in, const int* in_sizes, int n_in,
                              void* d_out, int out_size, void* d_ws, size_t ws_size,
                              hipStream_t stream) {
    const int* in = (const int*)d_in[0];
    int* out = (int*)d_out;  // output compared as int32 (uint8 ref stored as int32)

    const int npix = 512 * 512;
    const int ints_per_img = 3 * npix;
    const int n_img = in_sizes[0] / ints_per_img;  // 64

    equalize_fused<<<n_img * 3, 1024, 0, stream>>>(in, out, npix);
}

// Round 3
// 122.052 us; speedup vs baseline: 2.7046x; 2.7046x over previous
//
#include <hip/hip_runtime.h>

constexpr int NBINS = 256;
constexpr int HPI = 3 * NBINS;  // 768 bins per image (3 channels)

// ---------------- Kernel 1: per-image 3-channel histogram, int4 coalesced ----------------
// Element index e = 4*i  ->  channel of v.x is (4*i) % 3 == i % 3.
__global__ __launch_bounds__(256)
void hist_kernel(const int4* __restrict__ in, int* __restrict__ hist,
                 int n4_per_img, int blocks_per_img) {
    __shared__ int subh[4][HPI];  // per-wave sub-histograms, 12 KB
    const int tid = threadIdx.x;
    const int wave = tid >> 6;

    for (int i = tid; i < 4 * HPI; i += 256) ((int*)subh)[i] = 0;
    __syncthreads();

    const int img = blockIdx.x / blocks_per_img;
    const int blk = blockIdx.x % blocks_per_img;
    const int4* p = in + (size_t)img * n4_per_img;

    for (int i = blk * 256 + tid; i < n4_per_img; i += blocks_per_img * 256) {
        int4 v = p[i];
        int c0 = i % 3;
        int c1 = c0 + 1; if (c1 == 3) c1 = 0;
        int c2 = c1 + 1; if (c2 == 3) c2 = 0;
        int c3 = c2 + 1; if (c3 == 3) c3 = 0;
        atomicAdd(&subh[wave][c0 * NBINS + (v.x & 255)], 1);
        atomicAdd(&subh[wave][c1 * NBINS + (v.y & 255)], 1);
        atomicAdd(&subh[wave][c2 * NBINS + (v.z & 255)], 1);
        atomicAdd(&subh[wave][c3 * NBINS + (v.w & 255)], 1);
    }
    __syncthreads();

    int* gh = hist + (size_t)img * HPI;
    for (int e = tid; e < HPI; e += 256) {
        int s = subh[0][e] + subh[1][e] + subh[2][e] + subh[3][e];
        if (s) atomicAdd(&gh[e], s);
    }
}

// ---------------- Kernel 2: build 256-entry LUT per (img,channel) ----------------
__global__ __launch_bounds__(256)
void lut_kernel(const int* __restrict__ hist, int* __restrict__ lut) {
    __shared__ int cum[NBINS];
    __shared__ int lastNZ;
    const int t = threadIdx.x;
    const int base = blockIdx.x * NBINS;

    int h = hist[base + t];
    cum[t] = h;
    if (t == 0) lastNZ = 0;
    __syncthreads();
    if (h > 0) atomicMax(&lastNZ, t);

    // inclusive scan (Hillis-Steele)
    for (int off = 1; off < NBINS; off <<= 1) {
        int add = (t >= off) ? cum[t - off] : 0;
        __syncthreads();
        cum[t] += add;
        __syncthreads();
    }

    const int sum  = cum[NBINS - 1];
    const int last = lastNZ;
    const int hl   = cum[last] - (last > 0 ? cum[last - 1] : 0);  // histo[last]
    const int step = (sum - hl) / 255;

    int v;
    if (step == 0) {
        v = t;  // reference: where(step==0, img, ...)
    } else {
        // lut = concat([0], (cumsum+step//2)//step [:-1]) clipped -> exclusive prefix
        const int cp = (t == 0) ? 0 : cum[t - 1];
        v = (cp + (step >> 1)) / step;
        if (v > 255) v = 255;
    }
    lut[base + t] = v;
}

// ---------------- Kernel 3: apply LUT, int4 in / int4 out ----------------
__global__ __launch_bounds__(256)
void apply_kernel(const int4* __restrict__ in, int4* __restrict__ out,
                  const int* __restrict__ lut, int n4_per_img, int blocks_per_img) {
    __shared__ int l[HPI];
    const int tid = threadIdx.x;
    const int img = blockIdx.x / blocks_per_img;
    const int blk = blockIdx.x % blocks_per_img;

    const int* gl = lut + (size_t)img * HPI;
    for (int i = tid; i < HPI; i += 256) l[i] = gl[i];
    __syncthreads();

    const int4* p = in + (size_t)img * n4_per_img;
    int4* q = out + (size_t)img * n4_per_img;

    for (int i = blk * 256 + tid; i < n4_per_img; i += blocks_per_img * 256) {
        int4 v = p[i];
        int c0 = i % 3;
        int c1 = c0 + 1; if (c1 == 3) c1 = 0;
        int c2 = c1 + 1; if (c2 == 3) c2 = 0;
        int c3 = c2 + 1; if (c3 == 3) c3 = 0;
        int4 o;
        o.x = l[c0 * NBINS + (v.x & 255)];
        o.y = l[c1 * NBINS + (v.y & 255)];
        o.z = l[c2 * NBINS + (v.z & 255)];
        o.w = l[c3 * NBINS + (v.w & 255)];
        q[i] = o;
    }
}

extern "C" void kernel_launch(void* const* d_in, const int* in_sizes, int n_in,
                              void* d_out, int out_size, void* d_ws, size_t ws_size,
                              hipStream_t stream) {
    const int* in = (const int*)d_in[0];
    int* out = (int*)d_out;

    const int npix = 512 * 512;
    const int ints_per_img = 3 * npix;
    const int n4_per_img = ints_per_img / 4;          // 196608
    const int n_img = in_sizes[0] / ints_per_img;      // 64

    int* hist = (int*)d_ws;
    int* lut  = hist + (size_t)n_img * HPI;

    hipMemsetAsync(hist, 0, (size_t)n_img * HPI * sizeof(int), stream);

    const int bpi = 32;  // 64*32 = 2048 blocks -> 8 blocks/CU, full occupancy
    hist_kernel<<<n_img * bpi, 256, 0, stream>>>((const int4*)in, hist, n4_per_img, bpi);
    lut_kernel<<<n_img * 3, 256, 0, stream>>>(hist, lut);
    apply_kernel<<<n_img * bpi, 256, 0, stream>>>((const int4*)in, (int4*)out, lut, n4_per_img, bpi);
}

// Round 5
// 106.137 us; speedup vs baseline: 3.1102x; 1.1500x over previous
//
#include <hip/hip_runtime.h>

constexpr int NBINS = 256;
constexpr int HPI = 3 * NBINS;  // 768 bins per image (3 channels)

typedef int iv4 __attribute__((ext_vector_type(4)));  // native vector: OK for nontemporal builtins

// ---------------- Kernel 1: per-block partial histograms (no zero-init, no global atomics) ----
// Element index of v.x is 4*i; (4*i) % 3 == i % 3. With stride % 3 == 0 the
// channel phase of each thread is loop-invariant.
__global__ __launch_bounds__(256)
void hist_part_kernel(const iv4* __restrict__ in, int* __restrict__ part,
                      int n4_per_img, int bpi) {
    __shared__ int subh[4][HPI];  // per-wave sub-histograms, 12 KB
    const int tid = threadIdx.x;
    const int wave = tid >> 6;

    for (int i = tid; i < 4 * HPI; i += 256) ((int*)subh)[i] = 0;
    __syncthreads();

    const int img = blockIdx.x / bpi;
    const int blk = blockIdx.x % bpi;
    const iv4* p = in + (size_t)img * n4_per_img;
    const int stride = bpi * 256;  // divisible by 3 (bpi % 3 == 0)

    int i = blk * 256 + tid;
    int c0 = i % 3;
    int c1 = c0 + 1; if (c1 == 3) c1 = 0;
    int c2 = c1 + 1; if (c2 == 3) c2 = 0;
    int c3 = c2 + 1; if (c3 == 3) c3 = 0;
    const int b0 = c0 * NBINS, b1 = c1 * NBINS, b2 = c2 * NBINS, b3 = c3 * NBINS;

    for (; i < n4_per_img; i += stride) {
        iv4 v = p[i];
        atomicAdd(&subh[wave][b0 + (v.x & 255)], 1);
        atomicAdd(&subh[wave][b1 + (v.y & 255)], 1);
        atomicAdd(&subh[wave][b2 + (v.z & 255)], 1);
        atomicAdd(&subh[wave][b3 + (v.w & 255)], 1);
    }
    __syncthreads();

    int* gp = part + (size_t)blockIdx.x * HPI;  // own slot: plain store
    for (int e = tid; e < HPI; e += 256)
        gp[e] = subh[0][e] + subh[1][e] + subh[2][e] + subh[3][e];
}

// ---------------- Kernel 2: reduce partials + build LUT per (img,channel) ----------------
__global__ __launch_bounds__(256)
void lut_kernel(const int* __restrict__ part, int* __restrict__ lut, int npart) {
    __shared__ int cum[NBINS];
    __shared__ int lastNZ;
    const int t = threadIdx.x;
    const int img = blockIdx.x / 3;
    const int ch  = blockIdx.x % 3;

    const int* p = part + (size_t)img * npart * HPI + ch * NBINS + t;
    int h = 0;
    for (int b = 0; b < npart; ++b) h += p[(size_t)b * HPI];

    cum[t] = h;
    if (t == 0) lastNZ = 0;
    __syncthreads();
    if (h > 0) atomicMax(&lastNZ, t);

    for (int off = 1; off < NBINS; off <<= 1) {
        int add = (t >= off) ? cum[t - off] : 0;
        __syncthreads();
        cum[t] += add;
        __syncthreads();
    }

    const int sum  = cum[NBINS - 1];
    const int last = lastNZ;
    const int hl   = cum[last] - (last > 0 ? cum[last - 1] : 0);  // histo[last]
    const int step = (sum - hl) / 255;

    int v;
    if (step == 0) {
        v = t;  // reference: where(step==0, img, ...)
    } else {
        // lut = clip(concat([0], (cumsum+step//2)//step [:-1]), 0, 255)
        const int cp = (t == 0) ? 0 : cum[t - 1];
        v = (cp + (step >> 1)) / step;
        if (v > 255) v = 255;
    }
    lut[blockIdx.x * NBINS + t] = v;
}

// ---------------- Kernel 3: apply LUT, iv4 in / nt-iv4 out ----------------
__global__ __launch_bounds__(256)
void apply_kernel(const iv4* __restrict__ in, iv4* __restrict__ out,
                  const int* __restrict__ lut, int n4_per_img, int bpi) {
    __shared__ int l[HPI];
    const int tid = threadIdx.x;
    const int img = blockIdx.x / bpi;
    const int blk = blockIdx.x % bpi;

    const int* gl = lut + (size_t)img * HPI;
    for (int i = tid; i < HPI; i += 256) l[i] = gl[i];
    __syncthreads();

    const iv4* p = in + (size_t)img * n4_per_img;
    iv4* q = out + (size_t)img * n4_per_img;
    const int stride = bpi * 256;  // divisible by 3

    int i = blk * 256 + tid;
    int c0 = i % 3;
    int c1 = c0 + 1; if (c1 == 3) c1 = 0;
    int c2 = c1 + 1; if (c2 == 3) c2 = 0;
    int c3 = c2 + 1; if (c3 == 3) c3 = 0;
    const int b0 = c0 * NBINS, b1 = c1 * NBINS, b2 = c2 * NBINS, b3 = c3 * NBINS;

    for (; i < n4_per_img; i += stride) {
        iv4 v = p[i];
        iv4 o;
        o.x = l[b0 + (v.x & 255)];
        o.y = l[b1 + (v.y & 255)];
        o.z = l[b2 + (v.z & 255)];
        o.w = l[b3 + (v.w & 255)];
        __builtin_nontemporal_store(o, &q[i]);  // output never re-read: keep LLC for input
    }
}

extern "C" void kernel_launch(void* const* d_in, const int* in_sizes, int n_in,
                              void* d_out, int out_size, void* d_ws, size_t ws_size,
                              hipStream_t stream) {
    const int* in = (const int*)d_in[0];
    int* out = (int*)d_out;

    const int npix = 512 * 512;
    const int ints_per_img = 3 * npix;
    const int n4_per_img = ints_per_img / 4;        // 196608
    const int n_img = in_sizes[0] / ints_per_img;   // 64

    // pick largest hist bpi (multiple of 3) whose partials + lut fit d_ws
    int bpi_h = 48;
    while (bpi_h > 3) {
        size_t need = (size_t)n_img * bpi_h * HPI * sizeof(int)
                    + (size_t)n_img * HPI * sizeof(int);
        if (need <= ws_size) break;
        bpi_h -= (bpi_h > 24) ? 24 : ((bpi_h > 12) ? 12 : ((bpi_h > 6) ? 6 : 3));
    }

    int* part = (int*)d_ws;
    int* lut  = part + (size_t)n_img * bpi_h * HPI;

    hist_part_kernel<<<n_img * bpi_h, 256, 0, stream>>>((const iv4*)in, part, n4_per_img, bpi_h);
    lut_kernel<<<n_img * 3, 256, 0, stream>>>(part, lut, bpi_h);

    const int bpi_a = 48;  // 3072 blocks
    apply_kernel<<<n_img * bpi_a, 256, 0, stream>>>((const iv4*)in, (iv4*)out, lut, n4_per_img, bpi_a);
}

// Round 6
// 102.489 us; speedup vs baseline: 3.2209x; 1.0356x over previous
//
#include <hip/hip_runtime.h>

constexpr int NBINS = 256;
constexpr int HPI = 3 * NBINS;  // 768 bins per image (3 channels)

typedef int iv4 __attribute__((ext_vector_type(4)));  // native vector: OK for nontemporal builtins

// ---------------- Kernel 1: per-block partial histograms ----------------
// Element index of v.x is 4*i; (4*i) % 3 == i % 3. With stride % 3 == 0 the
// channel phase of each thread is loop-invariant. Unroll x2 for ILP.
__global__ __launch_bounds__(256)
void hist_part_kernel(const iv4* __restrict__ in, int* __restrict__ part,
                      int n4_per_img, int bpi) {
    __shared__ int subh[4][HPI];  // per-wave sub-histograms, 12 KB
    const int tid = threadIdx.x;
    const int wave = tid >> 6;

    for (int i = tid; i < 4 * HPI; i += 256) ((int*)subh)[i] = 0;
    __syncthreads();

    const int img = blockIdx.x / bpi;
    const int blk = blockIdx.x % bpi;
    const iv4* p = in + (size_t)img * n4_per_img;
    const int stride = bpi * 256;  // divisible by 3 (bpi % 3 == 0)

    int i = blk * 256 + tid;
    int c0 = i % 3;
    int c1 = c0 + 1; if (c1 == 3) c1 = 0;
    int c2 = c1 + 1; if (c2 == 3) c2 = 0;
    int c3 = c2 + 1; if (c3 == 3) c3 = 0;
    const int b0 = c0 * NBINS, b1 = c1 * NBINS, b2 = c2 * NBINS, b3 = c3 * NBINS;

    // unrolled x2: both loads issued before any LDS work (same channel phase)
    for (; i + stride < n4_per_img; i += 2 * stride) {
        iv4 v0 = p[i];
        iv4 v1 = p[i + stride];
        atomicAdd(&subh[wave][b0 + (v0.x & 255)], 1);
        atomicAdd(&subh[wave][b1 + (v0.y & 255)], 1);
        atomicAdd(&subh[wave][b2 + (v0.z & 255)], 1);
        atomicAdd(&subh[wave][b3 + (v0.w & 255)], 1);
        atomicAdd(&subh[wave][b0 + (v1.x & 255)], 1);
        atomicAdd(&subh[wave][b1 + (v1.y & 255)], 1);
        atomicAdd(&subh[wave][b2 + (v1.z & 255)], 1);
        atomicAdd(&subh[wave][b3 + (v1.w & 255)], 1);
    }
    if (i < n4_per_img) {
        iv4 v = p[i];
        atomicAdd(&subh[wave][b0 + (v.x & 255)], 1);
        atomicAdd(&subh[wave][b1 + (v.y & 255)], 1);
        atomicAdd(&subh[wave][b2 + (v.z & 255)], 1);
        atomicAdd(&subh[wave][b3 + (v.w & 255)], 1);
    }
    __syncthreads();

    int* gp = part + (size_t)blockIdx.x * HPI;  // own slot: plain store
    for (int e = tid; e < HPI; e += 256)
        gp[e] = subh[0][e] + subh[1][e] + subh[2][e] + subh[3][e];
}

// ---------------- Kernel 2: reduce partials + build LUT per (img,channel) ----------------
__global__ __launch_bounds__(256)
void lut_kernel(const int* __restrict__ part, int* __restrict__ lut, int npart) {
    __shared__ int cum[NBINS];
    __shared__ int lastNZ;
    const int t = threadIdx.x;
    const int img = blockIdx.x / 3;
    const int ch  = blockIdx.x % 3;

    const int* p = part + (size_t)img * npart * HPI + ch * NBINS + t;
    int h = 0;
    for (int b = 0; b < npart; ++b) h += p[(size_t)b * HPI];

    cum[t] = h;
    if (t == 0) lastNZ = 0;
    __syncthreads();
    if (h > 0) atomicMax(&lastNZ, t);

    for (int off = 1; off < NBINS; off <<= 1) {
        int add = (t >= off) ? cum[t - off] : 0;
        __syncthreads();
        cum[t] += add;
        __syncthreads();
    }

    const int sum  = cum[NBINS - 1];
    const int last = lastNZ;
    const int hl   = cum[last] - (last > 0 ? cum[last - 1] : 0);  // histo[last]
    const int step = (sum - hl) / 255;

    int v;
    if (step == 0) {
        v = t;  // reference: where(step==0, img, ...)
    } else {
        // lut = clip(concat([0], (cumsum+step//2)//step [:-1]), 0, 255)
        const int cp = (t == 0) ? 0 : cum[t - 1];
        v = (cp + (step >> 1)) / step;
        if (v > 255) v = 255;
    }
    lut[blockIdx.x * NBINS + t] = v;
}

// ---------------- Kernel 3: apply LUT, iv4 in / nt-iv4 out, unroll x2 ----------------
__global__ __launch_bounds__(256)
void apply_kernel(const iv4* __restrict__ in, iv4* __restrict__ out,
                  const int* __restrict__ lut, int n4_per_img, int bpi) {
    __shared__ int l[HPI];
    const int tid = threadIdx.x;
    const int img = blockIdx.x / bpi;
    const int blk = blockIdx.x % bpi;

    const int* gl = lut + (size_t)img * HPI;
    for (int i = tid; i < HPI; i += 256) l[i] = gl[i];
    __syncthreads();

    const iv4* p = in + (size_t)img * n4_per_img;
    iv4* q = out + (size_t)img * n4_per_img;
    const int stride = bpi * 256;  // divisible by 3

    int i = blk * 256 + tid;
    int c0 = i % 3;
    int c1 = c0 + 1; if (c1 == 3) c1 = 0;
    int c2 = c1 + 1; if (c2 == 3) c2 = 0;
    int c3 = c2 + 1; if (c3 == 3) c3 = 0;
    const int b0 = c0 * NBINS, b1 = c1 * NBINS, b2 = c2 * NBINS, b3 = c3 * NBINS;

    for (; i + stride < n4_per_img; i += 2 * stride) {
        iv4 v0 = p[i];
        iv4 v1 = p[i + stride];
        iv4 o0, o1;
        o0.x = l[b0 + (v0.x & 255)];
        o0.y = l[b1 + (v0.y & 255)];
        o0.z = l[b2 + (v0.z & 255)];
        o0.w = l[b3 + (v0.w & 255)];
        o1.x = l[b0 + (v1.x & 255)];
        o1.y = l[b1 + (v1.y & 255)];
        o1.z = l[b2 + (v1.z & 255)];
        o1.w = l[b3 + (v1.w & 255)];
        __builtin_nontemporal_store(o0, &q[i]);           // output never re-read:
        __builtin_nontemporal_store(o1, &q[i + stride]);  // keep LLC for input
    }
    if (i < n4_per_img) {
        iv4 v = p[i];
        iv4 o;
        o.x = l[b0 + (v.x & 255)];
        o.y = l[b1 + (v.y & 255)];
        o.z = l[b2 + (v.z & 255)];
        o.w = l[b3 + (v.w & 255)];
        __builtin_nontemporal_store(o, &q[i]);
    }
}

extern "C" void kernel_launch(void* const* d_in, const int* in_sizes, int n_in,
                              void* d_out, int out_size, void* d_ws, size_t ws_size,
                              hipStream_t stream) {
    const int* in = (const int*)d_in[0];
    int* out = (int*)d_out;

    const int npix = 512 * 512;
    const int ints_per_img = 3 * npix;
    const int n4_per_img = ints_per_img / 4;        // 196608
    const int n_img = in_sizes[0] / ints_per_img;   // 64

    // bpi=24 (multiple of 3): 64*24 = 1536 blocks = exactly 6 blocks/CU on 256 CUs,
    // 24 waves/CU in ONE scheduling round (48 waves/CU at bpi=48 needed two).
    int bpi_h = 24;
    while (bpi_h > 3) {
        size_t need = (size_t)n_img * bpi_h * HPI * sizeof(int)
                    + (size_t)n_img * HPI * sizeof(int);
        if (need <= ws_size) break;
        bpi_h -= (bpi_h > 12) ? 12 : ((bpi_h > 6) ? 6 : 3);
    }

    int* part = (int*)d_ws;
    int* lut  = part + (size_t)n_img * bpi_h * HPI;

    hist_part_kernel<<<n_img * bpi_h, 256, 0, stream>>>((const iv4*)in, part, n4_per_img, bpi_h);
    lut_kernel<<<n_img * 3, 256, 0, stream>>>(part, lut, bpi_h);

    const int bpi_a = 24;
    apply_kernel<<<n_img * bpi_a, 256, 0, stream>>>((const iv4*)in, (iv4*)out, lut, n4_per_img, bpi_a);
}